// Round 14
// baseline (193.073 us; speedup 1.0000x reference)
//
#include <hip/hip_runtime.h>
#include <math.h>

#define B_ 16
#define H_ 256
#define L_ 4096
#define N_ 64
#define HN (H_*N_)
#define HL (H_*L_)
#define BHL (B_*H_*L_)
#define SPAD 64

#define WVT_OFS 0
#define TM_OFS  8192
#define E2T_OFS 12288
#define MATS_PER 20480

typedef short bf16x8 __attribute__((ext_vector_type(8)));
typedef float f32x4  __attribute__((ext_vector_type(4)));

__device__ __forceinline__ unsigned int pk2(float a, float b) {
    return ((__float_as_uint(a) + 0x8000u) >> 16) |
           ((__float_as_uint(b) + 0x8000u) & 0xffff0000u);
}
__device__ __forceinline__ unsigned short bfr(float a) {
    return (unsigned short)((__float_as_uint(a) + 0x8000u) >> 16);
}
__device__ __forceinline__ float ubf(unsigned short u) {
    return __uint_as_float(((unsigned int)u) << 16);
}

// ---------------------------------------------------------------------------
// Kernel 1: build per-(h,dir) matrices + w^64. 1 wave per (h,dir).
// ---------------------------------------------------------------------------
__global__ void __launch_bounds__(64) mats_kernel(const float* __restrict__ log_dt,
                                                  const float* __restrict__ A_re,
                                                  const float* __restrict__ A_im,
                                                  const float* __restrict__ C_re,
                                                  const float* __restrict__ C_im,
                                                  unsigned short* __restrict__ mats,
                                                  float2* __restrict__ Wc) {
    int hd = blockIdx.x;
    int h = hd >> 1, d = hd & 1;
    int m = threadIdx.x;
    __shared__ float2 pws[65 * 64];
    __shared__ float2 c2s[64];
    __shared__ float  Karr[64];

    int i = h * 64 + m;
    float dt = expf(log_dt[h]);
    float Are = A_re[i], Aim = A_im[i];
    float dr = dt * Are, di = dt * Aim;
    float er = expf(dr);
    float wr = er * cosf(di), wi = er * sinf(di);
    float em1r = wr - 1.0f, em1i = wi;
    float inv = 1.0f / (Are * Are + Aim * Aim);
    float qr = (em1r * Are + em1i * Aim) * inv;
    float qi = (em1i * Are - em1r * Aim) * inv;
    float Cr = C_re[d * HN + i], Ci = C_im[d * HN + i];
    float2 c2;
    c2.x = 2.0f * (Cr * qr - Ci * qi);
    c2.y = 2.0f * (Cr * qi + Ci * qr);
    c2s[m] = c2;
    float pr = 1.0f, pi = 0.0f;
    for (int k = 0; k < 64; ++k) {
        float2 p; p.x = pr; p.y = pi;
        pws[k * 64 + ((m + k) & 63)] = p;
        float t = pr * wr - pi * wi;
        pi = pr * wi + pi * wr;
        pr = t;
    }
    {
        float2 p; p.x = pr; p.y = pi;
        pws[64 * 64 + ((m + 64) & 63)] = p;
        Wc[hd * 64 + m] = p;
    }
    __syncthreads();
    {
        float kk = 0.f;
        for (int mm = 0; mm < 64; ++mm) {
            float2 c = c2s[mm];
            float2 pw = pws[m * 64 + ((mm + m) & 63)];
            kk += c.x * pw.x - c.y * pw.y;
        }
        Karr[m] = kk;
    }
    __syncthreads();
    unsigned short* mb = mats + (size_t)hd * MATS_PER;
    for (int i2 = 0; i2 < 32; ++i2) {
        int e0 = 2 * i2, e1 = e0 + 1;
        int k0 = d ? e0 : 63 - e0;
        int k1 = d ? e1 : 63 - e1;
        float2 p0 = pws[k0 * 64 + ((m + k0) & 63)];
        float2 p1 = pws[k1 * 64 + ((m + k1) & 63)];
        *(unsigned int*)(mb + WVT_OFS + (2 * m) * 64 + e0)     = pk2(p0.x, p1.x);
        *(unsigned int*)(mb + WVT_OFS + (2 * m + 1) * 64 + e0) = pk2(p0.y, p1.y);
    }
    for (int i2 = 0; i2 < 32; ++i2) {
        int e0 = 2 * i2, e1 = e0 + 1;
        float v0, v1;
        if (d == 0) {
            v0 = (e0 <= m) ? Karr[m - e0] : 0.f;
            v1 = (e1 <= m) ? Karr[m - e1] : 0.f;
        } else {
            v0 = (e0 > m) ? Karr[e0 - m - 1] : 0.f;
            v1 = (e1 > m) ? Karr[e1 - m - 1] : 0.f;
        }
        *(unsigned int*)(mb + TM_OFS + m * 64 + e0) = pk2(v0, v1);
    }
    {
        int kp = d ? (63 - m) : (m + 1);
        for (int mm = 0; mm < 64; ++mm) {
            float2 c = c2s[mm];
            float2 pw = pws[kp * 64 + ((mm + kp) & 63)];
            float vr = c.x * pw.x - c.y * pw.y;
            float vi = -(c.x * pw.y + c.y * pw.x);
            *(unsigned int*)(mb + E2T_OFS + m * 128 + 2 * mm) = pk2(vr, vi);
        }
    }
}

// ---------------------------------------------------------------------------
// Kernel 1b: W fp32 -> bf16
// ---------------------------------------------------------------------------
__global__ void __launch_bounds__(256) wbf_kernel(const float* __restrict__ W,
                                                  unsigned short* __restrict__ Wbf) {
    int i = (blockIdx.x * 256 + threadIdx.x) * 4;
    float4 v = *(const float4*)(W + i);
    uint2 u;
    u.x = pk2(v.x, v.y);
    u.y = pk2(v.z, v.w);
    *(uint2*)(Wbf + i) = u;
}

// ---------------------------------------------------------------------------
// Kernel 2: LayerNorm over channel dim H; writes z bf16 AND x bf16 copy.
// ---------------------------------------------------------------------------
__global__ void __launch_bounds__(256) ln_kernel(const float* __restrict__ x,
                                                 const float* __restrict__ lnw,
                                                 const float* __restrict__ lnb,
                                                 unsigned short* __restrict__ zb,
                                                 unsigned short* __restrict__ xbf) {
    int b  = blockIdx.y;
    int l0 = blockIdx.x * 256;
    int t  = threadIdx.x;
    int hq = t >> 6, lo = t & 63;
    int l  = l0 + lo * 4;
    __shared__ float4 r1[4][64];
    __shared__ float4 r2[4][64];
    __shared__ float4 muS[64];
    __shared__ float4 rsS[64];
    const float* xb = x + (size_t)b * HL;
    float4 s1 = {0.f,0.f,0.f,0.f}, s2 = {0.f,0.f,0.f,0.f};
    #pragma unroll 4
    for (int hh = 0; hh < 64; ++hh) {
        int h = hq * 64 + hh;
        float4 v = *(const float4*)(xb + (size_t)h * L_ + l);
        s1.x += v.x; s1.y += v.y; s1.z += v.z; s1.w += v.w;
        s2.x += v.x*v.x; s2.y += v.y*v.y; s2.z += v.z*v.z; s2.w += v.w*v.w;
    }
    r1[hq][lo] = s1; r2[hq][lo] = s2;
    __syncthreads();
    if (t < 64) {
        float4 S1 = r1[0][t], S2 = r2[0][t];
        #pragma unroll
        for (int q = 1; q < 4; ++q) {
            float4 a = r1[q][t], c = r2[q][t];
            S1.x += a.x; S1.y += a.y; S1.z += a.z; S1.w += a.w;
            S2.x += c.x; S2.y += c.y; S2.z += c.z; S2.w += c.w;
        }
        const float invH = 1.0f / 256.0f;
        float4 mu, rs;
        mu.x = S1.x*invH; mu.y = S1.y*invH; mu.z = S1.z*invH; mu.w = S1.w*invH;
        rs.x = rsqrtf(S2.x*invH - mu.x*mu.x + 1e-5f);
        rs.y = rsqrtf(S2.y*invH - mu.y*mu.y + 1e-5f);
        rs.z = rsqrtf(S2.z*invH - mu.z*mu.z + 1e-5f);
        rs.w = rsqrtf(S2.w*invH - mu.w*mu.w + 1e-5f);
        muS[t] = mu; rsS[t] = rs;
    }
    __syncthreads();
    float4 mu = muS[lo], rs = rsS[lo];
    #pragma unroll 4
    for (int hh = 0; hh < 64; ++hh) {
        int h = hq * 64 + hh;
        float w = lnw[h], bb = lnb[h];
        float4 v = *(const float4*)(xb + (size_t)h * L_ + l);
        float4 zz;
        zz.x = (v.x - mu.x) * rs.x * w + bb;
        zz.y = (v.y - mu.y) * rs.y * w + bb;
        zz.z = (v.z - mu.z) * rs.z * w + bb;
        zz.w = (v.w - mu.w) * rs.w * w + bb;
        uint2 u;
        u.x = pk2(zz.x, zz.y);
        u.y = pk2(zz.z, zz.w);
        *(uint2*)(zb + (size_t)b * HL + (size_t)h * L_ + l) = u;
        uint2 ux;
        ux.x = pk2(v.x, v.y);
        ux.y = pk2(v.z, v.w);
        *(uint2*)(xbf + (size_t)b * HL + (size_t)h * L_ + l) = ux;
    }
}

// ---------------------------------------------------------------------------
// Kernel 3: per-(b,h,dir) MFMA chunked S4D. Split-scan across both waves.
// ---------------------------------------------------------------------------
#define MFMA16(a,b,c) __builtin_amdgcn_mfma_f32_16x16x32_bf16((a),(b),(c),0,0,0)
#define SU_BASE 8192
#define SMID_BASE 24576

__global__ void __launch_bounds__(128, 3) ssm_kernel(const unsigned short* __restrict__ zb,
                                                     const unsigned short* __restrict__ mats,
                                                     const float2* __restrict__ Wc,
                                                     const float* __restrict__ D,
                                                     unsigned short* __restrict__ y2) {
    int bhd = blockIdx.x;
    int d  = bhd & 1;
    int bh = bhd >> 1;
    int h  = bh & (H_ - 1);
    int t  = threadIdx.x;
    int w  = t >> 6, l = t & 63;
    int p  = w;

    __shared__ __align__(16) char smem[25088];   // +512 B for smid

    const unsigned short* mb = mats + (size_t)(h * 2 + d) * MATS_PER;

    {
        const char* zrow = (const char*)(zb + (size_t)bh * L_);
        #pragma unroll
        for (int k = 0; k < 4; ++k) {
            int row = w * 32 + k * 8 + (l >> 3);
            int chunk = (l & 7) ^ (row & 7);
            const char* src = zrow + row * 128 + chunk * 16;
            __builtin_amdgcn_global_load_lds(
                (const __attribute__((address_space(1))) unsigned int*)src,
                (__attribute__((address_space(3))) unsigned int*)(smem + w * 4096 + k * 1024),
                16, 0, 0);
        }
    }
    __syncthreads();

    bf16x8 za[4][2];
    int arow = l & 15;
    int koff = (l >> 4) * 8;
    #pragma unroll
    for (int cb = 0; cb < 4; ++cb) {
        int row = cb * 16 + arow;
        unsigned int sw = (row & 7) << 4;
        #pragma unroll
        for (int kb = 0; kb < 2; ++kb) {
            unsigned int byte = (unsigned)(row * 128 + (kb * 32 + koff) * 2) ^ sw;
            za[cb][kb] = *(bf16x8*)(smem + byte);
        }
    }

    char* sUd = smem + SU_BASE;
    #pragma unroll
    for (int mcb = 0; mcb < 4; ++mcb) {
        int mcblk = p * 4 + mcb;
        const unsigned short* wv = mb + WVT_OFS + (mcblk * 16 + arow) * 64 + koff;
        bf16x8 b0 = *(const bf16x8*)(wv);
        bf16x8 b1 = *(const bf16x8*)(wv + 32);
        #pragma unroll
        for (int cb = 0; cb < 4; ++cb) {
            f32x4 acc = {0.f, 0.f, 0.f, 0.f};
            acc = MFMA16(za[cb][0], b0, acc);
            acc = MFMA16(za[cb][1], b1, acc);
            int mc = mcblk * 16 + arow;
            #pragma unroll
            for (int rr = 0; rr < 4; ++rr) {
                int c = cb * 16 + (l >> 4) * 4 + rr;
                unsigned int byte = ((unsigned)(c * 256 + mc * 2)) ^ ((c & 7) << 4);
                *(unsigned short*)(sUd + byte) = bfr(acc[rr]);
            }
        }
    }
    __syncthreads();

    // ---- split scan: wave0 = first-processed half, wave1 = second half ----
    float2 w64 = Wc[(h * 2 + d) * 64 + l];
    float2* smid = (float2*)(smem + SMID_BASE);
    {
        float sr = 0.f, si = 0.f;
        int cbase = (d == 0) ? (p ? 32 : 0) : (p ? 31 : 63);
        int cstep = (d == 0) ? 1 : -1;
        for (int k = 0; k < 32; ++k) {
            int c = cbase + cstep * k;
            unsigned int byte = ((unsigned)(c * 256 + l * 4)) ^ ((c & 7) << 4);
            unsigned int uu = *(unsigned int*)(sUd + byte);
            float ur = __uint_as_float(uu << 16);
            float ui = __uint_as_float(uu & 0xffff0000u);
            *(unsigned int*)(sUd + byte) = pk2(sr, si);
            float nsr = fmaf(w64.x, sr, fmaf(-w64.y, si, ur));
            float nsi = fmaf(w64.x, si, fmaf(w64.y, sr, ui));
            sr = nsr; si = nsi;
        }
        if (p == 0) { float2 sm; sm.x = sr; sm.y = si; smid[l] = sm; }
    }
    __syncthreads();
    if (p == 1) {
        float2 sm = smid[l];
        float pr2 = 1.f, pi2 = 0.f;
        int cbase = (d == 0) ? 32 : 31;
        int cstep = (d == 0) ? 1 : -1;
        for (int k = 0; k < 32; ++k) {
            int c = cbase + cstep * k;
            unsigned int byte = ((unsigned)(c * 256 + l * 4)) ^ ((c & 7) << 4);
            unsigned int uu = *(unsigned int*)(sUd + byte);
            float tr_ = __uint_as_float(uu << 16);
            float ti_ = __uint_as_float(uu & 0xffff0000u);
            float cr_ = fmaf(pr2, sm.x, -pi2 * sm.y);
            float ci_ = fmaf(pr2, sm.y,  pi2 * sm.x);
            *(unsigned int*)(sUd + byte) = pk2(tr_ + cr_, ti_ + ci_);
            float npr = pr2 * w64.x - pi2 * w64.y;
            float npi = pr2 * w64.y + pi2 * w64.x;
            pr2 = npr; pi2 = npi;
        }
    }
    __syncthreads();

    f32x4 yacc[2][4];
    #pragma unroll
    for (int jb = 0; jb < 2; ++jb) {
        int jblk = p * 2 + jb;
        const unsigned short* tm = mb + TM_OFS + (jblk * 16 + arow) * 64 + koff;
        bf16x8 tb0 = *(const bf16x8*)(tm);
        bf16x8 tb1 = *(const bf16x8*)(tm + 32);
        const unsigned short* et = mb + E2T_OFS + (jblk * 16 + arow) * 128 + koff;
        bf16x8 eb0 = *(const bf16x8*)(et);
        bf16x8 eb1 = *(const bf16x8*)(et + 32);
        bf16x8 eb2 = *(const bf16x8*)(et + 64);
        bf16x8 eb3 = *(const bf16x8*)(et + 96);
        #pragma unroll
        for (int cb = 0; cb < 4; ++cb) {
            f32x4 acc = {0.f, 0.f, 0.f, 0.f};
            acc = MFMA16(za[cb][0], tb0, acc);
            acc = MFMA16(za[cb][1], tb1, acc);
            int row = cb * 16 + arow;
            unsigned int sw = (row & 7) << 4;
            bf16x8 sa0 = *(bf16x8*)(sUd + (((unsigned)(row * 256 + (0 * 32 + koff) * 2)) ^ sw));
            bf16x8 sa1 = *(bf16x8*)(sUd + (((unsigned)(row * 256 + (1 * 32 + koff) * 2)) ^ sw));
            bf16x8 sa2 = *(bf16x8*)(sUd + (((unsigned)(row * 256 + (2 * 32 + koff) * 2)) ^ sw));
            bf16x8 sa3 = *(bf16x8*)(sUd + (((unsigned)(row * 256 + (3 * 32 + koff) * 2)) ^ sw));
            acc = MFMA16(sa0, eb0, acc);
            acc = MFMA16(sa1, eb1, acc);
            acc = MFMA16(sa2, eb2, acc);
            acc = MFMA16(sa3, eb3, acc);
            yacc[jb][cb] = acc;
        }
    }
    __syncthreads();

    {
        float dv = D[h];
        #pragma unroll
        for (int jb = 0; jb < 2; ++jb) {
            int j = (p * 2 + jb) * 16 + arow;
            #pragma unroll
            for (int cb = 0; cb < 4; ++cb) {
                #pragma unroll
                for (int rr = 0; rr < 4; ++rr) {
                    int c = cb * 16 + (l >> 4) * 4 + rr;
                    unsigned int byte = ((unsigned)(c * 128 + j * 2)) ^ ((c & 7) << 4);
                    float val = yacc[jb][cb][rr];
                    if (d == 0) val += dv * ubf(*(unsigned short*)(smem + byte));
                    *(unsigned short*)(smem + byte) = bfr(val);
                }
            }
        }
    }
    __syncthreads();
    {
        int row = t >> 1, halfq = t & 1;
        unsigned int rsw = (row & 7) << 4;
        char* go = (char*)(y2 + ((size_t)bh * 2 + d) * L_);
        #pragma unroll
        for (int j = 0; j < 4; ++j) {
            unsigned int off = (unsigned)(row * 128 + halfq * 64 + j * 16);
            uint4 a = *(const uint4*)(smem + (off ^ rsw));
            *(uint4*)(go + off) = a;
        }
    }
}

// ---------------------------------------------------------------------------
// Kernel 4: out[b,o,l] = xbf + b_out[o] + sum_h W[o,h]*gelu(yf+yb).
// ---------------------------------------------------------------------------
__global__ void __launch_bounds__(256, 3) outproj_kernel(
        const unsigned short* __restrict__ y2,
        const unsigned short* __restrict__ Wbf,
        const unsigned short* __restrict__ xbf,
        const float* __restrict__ bias,
        float* __restrict__ out) {
    int b  = blockIdx.z;
    int o0 = blockIdx.y * 128;
    int l0 = blockIdx.x * 128;
    int t  = threadIdx.x;
    int w  = t >> 6, lane = t & 63;
    int wr = w >> 1, wc = w & 1;
    int l15 = lane & 15, q = lane >> 4;

    __shared__ __align__(16) char lds[34816];
    unsigned short* At = (unsigned short*)lds;
    unsigned short* Bt = (unsigned short*)(lds + 16384);

    f32x4 acc[4][4];
    #pragma unroll
    for (int i = 0; i < 4; ++i)
        #pragma unroll
        for (int j = 0; j < 4; ++j) acc[i][j] = (f32x4){0.f, 0.f, 0.f, 0.f};

    const unsigned short* Wb0 = Wbf + (size_t)o0 * 256;
    unsigned int swz = (unsigned)(l15 & 7) << 4;

    int h_loc = t >> 2, lq = t & 3;

    for (int kt = 0; kt < 4; ++kt) {
        int k0 = kt * 64;
        {
            const unsigned short* yb0 =
                y2 + (((size_t)b * H_ + k0 + h_loc) * 2) * L_ + l0 + lq * 32;
            uint4 f[4], g[4];
            #pragma unroll
            for (int j = 0; j < 4; ++j) f[j] = *(const uint4*)(yb0 + j * 8);
            #pragma unroll
            for (int j = 0; j < 4; ++j) g[j] = *(const uint4*)(yb0 + L_ + j * 8);
            #pragma unroll
            for (int j = 0; j < 4; ++j) {
                #pragma unroll
                for (int e = 0; e < 8; ++e) {
                    int l_loc = lq * 32 + j * 8 + e;
                    float y = ubf(((const unsigned short*)&f[j])[e]) +
                              ubf(((const unsigned short*)&g[j])[e]);
                    float inner = 0.7978845608028654f * (y + 0.044715f * y * y * y);
                    float en = __expf(-2.0f * inner);
                    float gv = y * __builtin_amdgcn_rcpf(1.0f + en);
                    *(unsigned short*)((char*)At +
                        (((unsigned)(l_loc * 128 + h_loc * 2)) ^ ((l_loc & 7) << 4))) = bfr(gv);
                }
            }
        }
        #pragma unroll
        for (int s = 0; s < 4; ++s) {
            int id = (w * 4 + s) * 64 + lane;
            int row = id >> 3, ch = id & 7;
            int chl = ch ^ (row & 7);
            uint4 vb = *(const uint4*)(Wb0 + (size_t)row * 256 + k0 + chl * 8);
            *(uint4*)(Bt + id * 8) = vb;
        }
        __syncthreads();
        #pragma unroll
        for (int kk = 0; kk < 2; ++kk) {
            bf16x8 af[4], bfr_[4];
            #pragma unroll
            for (int rb = 0; rb < 4; ++rb) {
                int li = wr * 64 + rb * 16 + l15;
                af[rb] = *(const bf16x8*)((char*)At + li * 128 + (((kk * 64 + q * 16)) ^ swz));
                int oi = wc * 64 + rb * 16 + l15;
                bfr_[rb] = *(const bf16x8*)((char*)Bt + oi * 128 + (((kk * 64 + q * 16)) ^ swz));
            }
            #pragma unroll
            for (int rb = 0; rb < 4; ++rb)
                #pragma unroll
                for (int cb = 0; cb < 4; ++cb)
                    acc[rb][cb] = MFMA16(af[rb], bfr_[cb], acc[rb][cb]);
        }
        __syncthreads();
    }

    float* Eb = (float*)lds;
    for (int pp = 0; pp < 2; ++pp) {
        if (wc == pp) {
            #pragma unroll
            for (int cb = 0; cb < 4; ++cb) {
                int o_loc = cb * 16 + l15;
                unsigned int esw = (unsigned)(o_loc & 7) << 4;
                #pragma unroll
                for (int rb = 0; rb < 4; ++rb) {
                    int colbase = wr * 64 + rb * 16 + q * 4;
                    #pragma unroll
                    for (int r = 0; r < 4; ++r) {
                        int col = colbase + r;
                        *(float*)((char*)Eb + o_loc * 528 + (((unsigned)(col * 4)) ^ esw)) =
                            acc[rb][cb][r];
                    }
                }
            }
        }
        __syncthreads();
        int o_loc = t >> 2, lseg = t & 3;
        int o = o0 + pp * 64 + o_loc;
        float bo = bias[o];
        unsigned int esw = (unsigned)(o_loc & 7) << 4;
        size_t off = ((size_t)b * H_ + o) * L_ + l0 + lseg * 32;
        const unsigned short* xr = xbf + off;
        float* orow = out + off;
        #pragma unroll
        for (int j = 0; j < 8; ++j) {
            float4 e = *(const float4*)((char*)Eb + o_loc * 528 +
                                        (((unsigned)(lseg * 128 + j * 16)) ^ esw));
            uint2 xv2 = *(const uint2*)(xr + j * 4);
            float4 ov;
            ov.x = ubf((unsigned short)(xv2.x & 0xffffu))  + bo + e.x;
            ov.y = ubf((unsigned short)(xv2.x >> 16))      + bo + e.y;
            ov.z = ubf((unsigned short)(xv2.y & 0xffffu))  + bo + e.z;
            ov.w = ubf((unsigned short)(xv2.y >> 16))      + bo + e.w;
            *(float4*)(orow + j * 4) = ov;
        }
        __syncthreads();
    }
}

// ---------------------------------------------------------------------------
extern "C" void kernel_launch(void* const* d_in, const int* in_sizes, int n_in,
                              void* d_out, int out_size, void* d_ws, size_t ws_size,
                              hipStream_t stream) {
    const float* x      = (const float*)d_in[0];
    const float* log_dt = (const float*)d_in[1];
    const float* A_re   = (const float*)d_in[2];
    const float* A_im   = (const float*)d_in[3];
    const float* C_re   = (const float*)d_in[4];
    const float* C_im   = (const float*)d_in[5];
    const float* D      = (const float*)d_in[6];
    const float* lnw    = (const float*)d_in[7];
    const float* lnb    = (const float*)d_in[8];
    const float* W      = (const float*)d_in[9];
    const float* bout   = (const float*)d_in[10];
    float* out = (float*)d_out;

    unsigned short* zb   = (unsigned short*)d_ws;               // BHL bf16
    unsigned short* y2   = zb + (size_t)BHL + SPAD;             // 2*BHL bf16
    unsigned short* xbf  = y2 + 2 * (size_t)BHL + SPAD;         // BHL bf16
    unsigned short* mats = xbf + (size_t)BHL + SPAD;            // 512*20480 bf16
    float2* Wc = (float2*)(mats + 512 * (size_t)MATS_PER);      // 512*64 cplx
    unsigned short* Wbf = (unsigned short*)(Wc + 512 * 64);     // 65536 bf16

    mats_kernel<<<512, 64, 0, stream>>>(log_dt, A_re, A_im, C_re, C_im, mats, Wc);
    wbf_kernel<<<64, 256, 0, stream>>>(W, Wbf);
    ln_kernel<<<dim3(L_ / 256, B_), 256, 0, stream>>>(x, lnw, lnb, zb, xbf);
    ssm_kernel<<<B_ * H_ * 2, 128, 0, stream>>>(zb, mats, Wc, D, y2);
    outproj_kernel<<<dim3(L_ / 128, H_ / 128, B_), 256, 0, stream>>>(y2, Wbf, xbf, bout, out);
}

// Round 15
// 192.225 us; speedup vs baseline: 1.0044x; 1.0044x over previous
//
#include <hip/hip_runtime.h>
#include <math.h>

#define B_ 16
#define H_ 256
#define L_ 4096
#define N_ 64
#define HN (H_*N_)
#define HL (H_*L_)
#define BHL (B_*H_*L_)
#define SPAD 64

#define WVT_OFS 0
#define TM_OFS  8192
#define E2T_OFS 12288
#define MATS_PER 20480

typedef short bf16x8 __attribute__((ext_vector_type(8)));
typedef float f32x4  __attribute__((ext_vector_type(4)));

__device__ __forceinline__ unsigned int pk2(float a, float b) {
    return ((__float_as_uint(a) + 0x8000u) >> 16) |
           ((__float_as_uint(b) + 0x8000u) & 0xffff0000u);
}
__device__ __forceinline__ unsigned short bfr(float a) {
    return (unsigned short)((__float_as_uint(a) + 0x8000u) >> 16);
}
__device__ __forceinline__ float ubf(unsigned short u) {
    return __uint_as_float(((unsigned int)u) << 16);
}

// ---------------------------------------------------------------------------
// Kernel 1: build per-(h,dir) matrices + w^64. 1 wave per (h,dir).
// ---------------------------------------------------------------------------
__global__ void __launch_bounds__(64) mats_kernel(const float* __restrict__ log_dt,
                                                  const float* __restrict__ A_re,
                                                  const float* __restrict__ A_im,
                                                  const float* __restrict__ C_re,
                                                  const float* __restrict__ C_im,
                                                  unsigned short* __restrict__ mats,
                                                  float2* __restrict__ Wc) {
    int hd = blockIdx.x;
    int h = hd >> 1, d = hd & 1;
    int m = threadIdx.x;
    __shared__ float2 pws[65 * 64];
    __shared__ float2 c2s[64];
    __shared__ float  Karr[64];

    int i = h * 64 + m;
    float dt = expf(log_dt[h]);
    float Are = A_re[i], Aim = A_im[i];
    float dr = dt * Are, di = dt * Aim;
    float er = expf(dr);
    float wr = er * cosf(di), wi = er * sinf(di);
    float em1r = wr - 1.0f, em1i = wi;
    float inv = 1.0f / (Are * Are + Aim * Aim);
    float qr = (em1r * Are + em1i * Aim) * inv;
    float qi = (em1i * Are - em1r * Aim) * inv;
    float Cr = C_re[d * HN + i], Ci = C_im[d * HN + i];
    float2 c2;
    c2.x = 2.0f * (Cr * qr - Ci * qi);
    c2.y = 2.0f * (Cr * qi + Ci * qr);
    c2s[m] = c2;
    float pr = 1.0f, pi = 0.0f;
    for (int k = 0; k < 64; ++k) {
        float2 p; p.x = pr; p.y = pi;
        pws[k * 64 + ((m + k) & 63)] = p;
        float t = pr * wr - pi * wi;
        pi = pr * wi + pi * wr;
        pr = t;
    }
    {
        float2 p; p.x = pr; p.y = pi;
        pws[64 * 64 + ((m + 64) & 63)] = p;
        Wc[hd * 64 + m] = p;
    }
    __syncthreads();
    {
        float kk = 0.f;
        for (int mm = 0; mm < 64; ++mm) {
            float2 c = c2s[mm];
            float2 pw = pws[m * 64 + ((mm + m) & 63)];
            kk += c.x * pw.x - c.y * pw.y;
        }
        Karr[m] = kk;
    }
    __syncthreads();
    unsigned short* mb = mats + (size_t)hd * MATS_PER;
    for (int i2 = 0; i2 < 32; ++i2) {
        int e0 = 2 * i2, e1 = e0 + 1;
        int k0 = d ? e0 : 63 - e0;
        int k1 = d ? e1 : 63 - e1;
        float2 p0 = pws[k0 * 64 + ((m + k0) & 63)];
        float2 p1 = pws[k1 * 64 + ((m + k1) & 63)];
        *(unsigned int*)(mb + WVT_OFS + (2 * m) * 64 + e0)     = pk2(p0.x, p1.x);
        *(unsigned int*)(mb + WVT_OFS + (2 * m + 1) * 64 + e0) = pk2(p0.y, p1.y);
    }
    for (int i2 = 0; i2 < 32; ++i2) {
        int e0 = 2 * i2, e1 = e0 + 1;
        float v0, v1;
        if (d == 0) {
            v0 = (e0 <= m) ? Karr[m - e0] : 0.f;
            v1 = (e1 <= m) ? Karr[m - e1] : 0.f;
        } else {
            v0 = (e0 > m) ? Karr[e0 - m - 1] : 0.f;
            v1 = (e1 > m) ? Karr[e1 - m - 1] : 0.f;
        }
        *(unsigned int*)(mb + TM_OFS + m * 64 + e0) = pk2(v0, v1);
    }
    {
        int kp = d ? (63 - m) : (m + 1);
        for (int mm = 0; mm < 64; ++mm) {
            float2 c = c2s[mm];
            float2 pw = pws[kp * 64 + ((mm + kp) & 63)];
            float vr = c.x * pw.x - c.y * pw.y;
            float vi = -(c.x * pw.y + c.y * pw.x);
            *(unsigned int*)(mb + E2T_OFS + m * 128 + 2 * mm) = pk2(vr, vi);
        }
    }
}

// ---------------------------------------------------------------------------
// Kernel 1b: W fp32 -> bf16
// ---------------------------------------------------------------------------
__global__ void __launch_bounds__(256) wbf_kernel(const float* __restrict__ W,
                                                  unsigned short* __restrict__ Wbf) {
    int i = (blockIdx.x * 256 + threadIdx.x) * 4;
    float4 v = *(const float4*)(W + i);
    uint2 u;
    u.x = pk2(v.x, v.y);
    u.y = pk2(v.z, v.w);
    *(uint2*)(Wbf + i) = u;
}

// ---------------------------------------------------------------------------
// Kernel 2: LayerNorm over channel dim H; writes z bf16 AND x bf16 copy.
// ---------------------------------------------------------------------------
__global__ void __launch_bounds__(256) ln_kernel(const float* __restrict__ x,
                                                 const float* __restrict__ lnw,
                                                 const float* __restrict__ lnb,
                                                 unsigned short* __restrict__ zb,
                                                 unsigned short* __restrict__ xbf) {
    int b  = blockIdx.y;
    int l0 = blockIdx.x * 256;
    int t  = threadIdx.x;
    int hq = t >> 6, lo = t & 63;
    int l  = l0 + lo * 4;
    __shared__ float4 r1[4][64];
    __shared__ float4 r2[4][64];
    __shared__ float4 muS[64];
    __shared__ float4 rsS[64];
    const float* xb = x + (size_t)b * HL;
    float4 s1 = {0.f,0.f,0.f,0.f}, s2 = {0.f,0.f,0.f,0.f};
    #pragma unroll 4
    for (int hh = 0; hh < 64; ++hh) {
        int h = hq * 64 + hh;
        float4 v = *(const float4*)(xb + (size_t)h * L_ + l);
        s1.x += v.x; s1.y += v.y; s1.z += v.z; s1.w += v.w;
        s2.x += v.x*v.x; s2.y += v.y*v.y; s2.z += v.z*v.z; s2.w += v.w*v.w;
    }
    r1[hq][lo] = s1; r2[hq][lo] = s2;
    __syncthreads();
    if (t < 64) {
        float4 S1 = r1[0][t], S2 = r2[0][t];
        #pragma unroll
        for (int q = 1; q < 4; ++q) {
            float4 a = r1[q][t], c = r2[q][t];
            S1.x += a.x; S1.y += a.y; S1.z += a.z; S1.w += a.w;
            S2.x += c.x; S2.y += c.y; S2.z += c.z; S2.w += c.w;
        }
        const float invH = 1.0f / 256.0f;
        float4 mu, rs;
        mu.x = S1.x*invH; mu.y = S1.y*invH; mu.z = S1.z*invH; mu.w = S1.w*invH;
        rs.x = rsqrtf(S2.x*invH - mu.x*mu.x + 1e-5f);
        rs.y = rsqrtf(S2.y*invH - mu.y*mu.y + 1e-5f);
        rs.z = rsqrtf(S2.z*invH - mu.z*mu.z + 1e-5f);
        rs.w = rsqrtf(S2.w*invH - mu.w*mu.w + 1e-5f);
        muS[t] = mu; rsS[t] = rs;
    }
    __syncthreads();
    float4 mu = muS[lo], rs = rsS[lo];
    #pragma unroll 4
    for (int hh = 0; hh < 64; ++hh) {
        int h = hq * 64 + hh;
        float w = lnw[h], bb = lnb[h];
        float4 v = *(const float4*)(xb + (size_t)h * L_ + l);
        float4 zz;
        zz.x = (v.x - mu.x) * rs.x * w + bb;
        zz.y = (v.y - mu.y) * rs.y * w + bb;
        zz.z = (v.z - mu.z) * rs.z * w + bb;
        zz.w = (v.w - mu.w) * rs.w * w + bb;
        uint2 u;
        u.x = pk2(zz.x, zz.y);
        u.y = pk2(zz.z, zz.w);
        *(uint2*)(zb + (size_t)b * HL + (size_t)h * L_ + l) = u;
        uint2 ux;
        ux.x = pk2(v.x, v.y);
        ux.y = pk2(v.z, v.w);
        *(uint2*)(xbf + (size_t)b * HL + (size_t)h * L_ + l) = ux;
    }
}

// ---------------------------------------------------------------------------
// Kernel 3: per-(b,h,dir) MFMA chunked S4D (R13-proven single-wave scan).
// dir-0 block folds in D[h]*z. Writes y into unified y2[bh][dir][l].
// ---------------------------------------------------------------------------
#define MFMA16(a,b,c) __builtin_amdgcn_mfma_f32_16x16x32_bf16((a),(b),(c),0,0,0)
#define SU_BASE 8192

__global__ void __launch_bounds__(128, 3) ssm_kernel(const unsigned short* __restrict__ zb,
                                                     const unsigned short* __restrict__ mats,
                                                     const float2* __restrict__ Wc,
                                                     const float* __restrict__ D,
                                                     unsigned short* __restrict__ y2) {
    int bhd = blockIdx.x;
    int d  = bhd & 1;
    int bh = bhd >> 1;
    int h  = bh & (H_ - 1);
    int t  = threadIdx.x;
    int w  = t >> 6, l = t & 63;
    int p  = w;

    __shared__ __align__(16) char smem[24576];

    const unsigned short* mb = mats + (size_t)(h * 2 + d) * MATS_PER;

    {
        const char* zrow = (const char*)(zb + (size_t)bh * L_);
        #pragma unroll
        for (int k = 0; k < 4; ++k) {
            int row = w * 32 + k * 8 + (l >> 3);
            int chunk = (l & 7) ^ (row & 7);
            const char* src = zrow + row * 128 + chunk * 16;
            __builtin_amdgcn_global_load_lds(
                (const __attribute__((address_space(1))) unsigned int*)src,
                (__attribute__((address_space(3))) unsigned int*)(smem + w * 4096 + k * 1024),
                16, 0, 0);
        }
    }
    __syncthreads();

    bf16x8 za[4][2];
    int arow = l & 15;
    int koff = (l >> 4) * 8;
    #pragma unroll
    for (int cb = 0; cb < 4; ++cb) {
        int row = cb * 16 + arow;
        unsigned int sw = (row & 7) << 4;
        #pragma unroll
        for (int kb = 0; kb < 2; ++kb) {
            unsigned int byte = (unsigned)(row * 128 + (kb * 32 + koff) * 2) ^ sw;
            za[cb][kb] = *(bf16x8*)(smem + byte);
        }
    }

    char* sUd = smem + SU_BASE;
    #pragma unroll
    for (int mcb = 0; mcb < 4; ++mcb) {
        int mcblk = p * 4 + mcb;
        const unsigned short* wv = mb + WVT_OFS + (mcblk * 16 + arow) * 64 + koff;
        bf16x8 b0 = *(const bf16x8*)(wv);
        bf16x8 b1 = *(const bf16x8*)(wv + 32);
        #pragma unroll
        for (int cb = 0; cb < 4; ++cb) {
            f32x4 acc = {0.f, 0.f, 0.f, 0.f};
            acc = MFMA16(za[cb][0], b0, acc);
            acc = MFMA16(za[cb][1], b1, acc);
            int mc = mcblk * 16 + arow;
            #pragma unroll
            for (int rr = 0; rr < 4; ++rr) {
                int c = cb * 16 + (l >> 4) * 4 + rr;
                unsigned int byte = ((unsigned)(c * 256 + mc * 2)) ^ ((c & 7) << 4);
                *(unsigned short*)(sUd + byte) = bfr(acc[rr]);
            }
        }
    }
    __syncthreads();

    if (p == 0) {
        float2 w64 = Wc[(h * 2 + d) * 64 + l];
        float sr = 0.f, si = 0.f;
        if (d == 0) {
            for (int c = 0; c < 64; ++c) {
                unsigned int byte = ((unsigned)(c * 256 + l * 4)) ^ ((c & 7) << 4);
                unsigned int uu = *(unsigned int*)(sUd + byte);
                float ur = __uint_as_float(uu << 16);
                float ui = __uint_as_float(uu & 0xffff0000u);
                *(unsigned int*)(sUd + byte) = pk2(sr, si);
                float nsr = fmaf(w64.x, sr, fmaf(-w64.y, si, ur));
                float nsi = fmaf(w64.x, si, fmaf(w64.y, sr, ui));
                sr = nsr; si = nsi;
            }
        } else {
            for (int c = 63; c >= 0; --c) {
                unsigned int byte = ((unsigned)(c * 256 + l * 4)) ^ ((c & 7) << 4);
                unsigned int uu = *(unsigned int*)(sUd + byte);
                float ur = __uint_as_float(uu << 16);
                float ui = __uint_as_float(uu & 0xffff0000u);
                *(unsigned int*)(sUd + byte) = pk2(sr, si);
                float nsr = fmaf(w64.x, sr, fmaf(-w64.y, si, ur));
                float nsi = fmaf(w64.x, si, fmaf(w64.y, sr, ui));
                sr = nsr; si = nsi;
            }
        }
    }
    __syncthreads();

    f32x4 yacc[2][4];
    #pragma unroll
    for (int jb = 0; jb < 2; ++jb) {
        int jblk = p * 2 + jb;
        const unsigned short* tm = mb + TM_OFS + (jblk * 16 + arow) * 64 + koff;
        bf16x8 tb0 = *(const bf16x8*)(tm);
        bf16x8 tb1 = *(const bf16x8*)(tm + 32);
        const unsigned short* et = mb + E2T_OFS + (jblk * 16 + arow) * 128 + koff;
        bf16x8 eb0 = *(const bf16x8*)(et);
        bf16x8 eb1 = *(const bf16x8*)(et + 32);
        bf16x8 eb2 = *(const bf16x8*)(et + 64);
        bf16x8 eb3 = *(const bf16x8*)(et + 96);
        #pragma unroll
        for (int cb = 0; cb < 4; ++cb) {
            f32x4 acc = {0.f, 0.f, 0.f, 0.f};
            acc = MFMA16(za[cb][0], tb0, acc);
            acc = MFMA16(za[cb][1], tb1, acc);
            int row = cb * 16 + arow;
            unsigned int sw = (row & 7) << 4;
            bf16x8 sa0 = *(bf16x8*)(sUd + (((unsigned)(row * 256 + (0 * 32 + koff) * 2)) ^ sw));
            bf16x8 sa1 = *(bf16x8*)(sUd + (((unsigned)(row * 256 + (1 * 32 + koff) * 2)) ^ sw));
            bf16x8 sa2 = *(bf16x8*)(sUd + (((unsigned)(row * 256 + (2 * 32 + koff) * 2)) ^ sw));
            bf16x8 sa3 = *(bf16x8*)(sUd + (((unsigned)(row * 256 + (3 * 32 + koff) * 2)) ^ sw));
            acc = MFMA16(sa0, eb0, acc);
            acc = MFMA16(sa1, eb1, acc);
            acc = MFMA16(sa2, eb2, acc);
            acc = MFMA16(sa3, eb3, acc);
            yacc[jb][cb] = acc;
        }
    }
    __syncthreads();

    {
        float dv = D[h];
        #pragma unroll
        for (int jb = 0; jb < 2; ++jb) {
            int j = (p * 2 + jb) * 16 + arow;
            #pragma unroll
            for (int cb = 0; cb < 4; ++cb) {
                #pragma unroll
                for (int rr = 0; rr < 4; ++rr) {
                    int c = cb * 16 + (l >> 4) * 4 + rr;
                    unsigned int byte = ((unsigned)(c * 128 + j * 2)) ^ ((c & 7) << 4);
                    float val = yacc[jb][cb][rr];
                    if (d == 0) val += dv * ubf(*(unsigned short*)(smem + byte));
                    *(unsigned short*)(smem + byte) = bfr(val);
                }
            }
        }
    }
    __syncthreads();
    {
        int row = t >> 1, halfq = t & 1;
        unsigned int rsw = (row & 7) << 4;
        char* go = (char*)(y2 + ((size_t)bh * 2 + d) * L_);
        #pragma unroll
        for (int j = 0; j < 4; ++j) {
            unsigned int off = (unsigned)(row * 128 + halfq * 64 + j * 16);
            uint4 a = *(const uint4*)(smem + (off ^ rsw));
            *(uint4*)(go + off) = a;
        }
    }
}

// ---------------------------------------------------------------------------
// Kernel 4: out[b,o,l] = xbf + b_out[o] + sum_h W[o,h]*gelu(yf+yb).
// ---------------------------------------------------------------------------
__global__ void __launch_bounds__(256, 3) outproj_kernel(
        const unsigned short* __restrict__ y2,
        const unsigned short* __restrict__ Wbf,
        const unsigned short* __restrict__ xbf,
        const float* __restrict__ bias,
        float* __restrict__ out) {
    int b  = blockIdx.z;
    int o0 = blockIdx.y * 128;
    int l0 = blockIdx.x * 128;
    int t  = threadIdx.x;
    int w  = t >> 6, lane = t & 63;
    int wr = w >> 1, wc = w & 1;
    int l15 = lane & 15, q = lane >> 4;

    __shared__ __align__(16) char lds[34816];
    unsigned short* At = (unsigned short*)lds;
    unsigned short* Bt = (unsigned short*)(lds + 16384);

    f32x4 acc[4][4];
    #pragma unroll
    for (int i = 0; i < 4; ++i)
        #pragma unroll
        for (int j = 0; j < 4; ++j) acc[i][j] = (f32x4){0.f, 0.f, 0.f, 0.f};

    const unsigned short* Wb0 = Wbf + (size_t)o0 * 256;
    unsigned int swz = (unsigned)(l15 & 7) << 4;

    int h_loc = t >> 2, lq = t & 3;

    for (int kt = 0; kt < 4; ++kt) {
        int k0 = kt * 64;
        {
            const unsigned short* yb0 =
                y2 + (((size_t)b * H_ + k0 + h_loc) * 2) * L_ + l0 + lq * 32;
            uint4 f[4], g[4];
            #pragma unroll
            for (int j = 0; j < 4; ++j) f[j] = *(const uint4*)(yb0 + j * 8);
            #pragma unroll
            for (int j = 0; j < 4; ++j) g[j] = *(const uint4*)(yb0 + L_ + j * 8);
            #pragma unroll
            for (int j = 0; j < 4; ++j) {
                #pragma unroll
                for (int e = 0; e < 8; ++e) {
                    int l_loc = lq * 32 + j * 8 + e;
                    float y = ubf(((const unsigned short*)&f[j])[e]) +
                              ubf(((const unsigned short*)&g[j])[e]);
                    float inner = 0.7978845608028654f * (y + 0.044715f * y * y * y);
                    float en = __expf(-2.0f * inner);
                    float gv = y * __builtin_amdgcn_rcpf(1.0f + en);
                    *(unsigned short*)((char*)At +
                        (((unsigned)(l_loc * 128 + h_loc * 2)) ^ ((l_loc & 7) << 4))) = bfr(gv);
                }
            }
        }
        #pragma unroll
        for (int s = 0; s < 4; ++s) {
            int id = (w * 4 + s) * 64 + lane;
            int row = id >> 3, ch = id & 7;
            int chl = ch ^ (row & 7);
            uint4 vb = *(const uint4*)(Wb0 + (size_t)row * 256 + k0 + chl * 8);
            *(uint4*)(Bt + id * 8) = vb;
        }
        __syncthreads();
        #pragma unroll
        for (int kk = 0; kk < 2; ++kk) {
            bf16x8 af[4], bfr_[4];
            #pragma unroll
            for (int rb = 0; rb < 4; ++rb) {
                int li = wr * 64 + rb * 16 + l15;
                af[rb] = *(const bf16x8*)((char*)At + li * 128 + (((kk * 64 + q * 16)) ^ swz));
                int oi = wc * 64 + rb * 16 + l15;
                bfr_[rb] = *(const bf16x8*)((char*)Bt + oi * 128 + (((kk * 64 + q * 16)) ^ swz));
            }
            #pragma unroll
            for (int rb = 0; rb < 4; ++rb)
                #pragma unroll
                for (int cb = 0; cb < 4; ++cb)
                    acc[rb][cb] = MFMA16(af[rb], bfr_[cb], acc[rb][cb]);
        }
        __syncthreads();
    }

    float* Eb = (float*)lds;
    for (int pp = 0; pp < 2; ++pp) {
        if (wc == pp) {
            #pragma unroll
            for (int cb = 0; cb < 4; ++cb) {
                int o_loc = cb * 16 + l15;
                unsigned int esw = (unsigned)(o_loc & 7) << 4;
                #pragma unroll
                for (int rb = 0; rb < 4; ++rb) {
                    int colbase = wr * 64 + rb * 16 + q * 4;
                    #pragma unroll
                    for (int r = 0; r < 4; ++r) {
                        int col = colbase + r;
                        *(float*)((char*)Eb + o_loc * 528 + (((unsigned)(col * 4)) ^ esw)) =
                            acc[rb][cb][r];
                    }
                }
            }
        }
        __syncthreads();
        int o_loc = t >> 2, lseg = t & 3;
        int o = o0 + pp * 64 + o_loc;
        float bo = bias[o];
        unsigned int esw = (unsigned)(o_loc & 7) << 4;
        size_t off = ((size_t)b * H_ + o) * L_ + l0 + lseg * 32;
        const unsigned short* xr = xbf + off;
        float* orow = out + off;
        #pragma unroll
        for (int j = 0; j < 8; ++j) {
            float4 e = *(const float4*)((char*)Eb + o_loc * 528 +
                                        (((unsigned)(lseg * 128 + j * 16)) ^ esw));
            uint2 xv2 = *(const uint2*)(xr + j * 4);
            float4 ov;
            ov.x = ubf((unsigned short)(xv2.x & 0xffffu))  + bo + e.x;
            ov.y = ubf((unsigned short)(xv2.x >> 16))      + bo + e.y;
            ov.z = ubf((unsigned short)(xv2.y & 0xffffu))  + bo + e.z;
            ov.w = ubf((unsigned short)(xv2.y >> 16))      + bo + e.w;
            *(float4*)(orow + j * 4) = ov;
        }
        __syncthreads();
    }
}

// ---------------------------------------------------------------------------
extern "C" void kernel_launch(void* const* d_in, const int* in_sizes, int n_in,
                              void* d_out, int out_size, void* d_ws, size_t ws_size,
                              hipStream_t stream) {
    const float* x      = (const float*)d_in[0];
    const float* log_dt = (const float*)d_in[1];
    const float* A_re   = (const float*)d_in[2];
    const float* A_im   = (const float*)d_in[3];
    const float* C_re   = (const float*)d_in[4];
    const float* C_im   = (const float*)d_in[5];
    const float* D      = (const float*)d_in[6];
    const float* lnw    = (const float*)d_in[7];
    const float* lnb    = (const float*)d_in[8];
    const float* W      = (const float*)d_in[9];
    const float* bout   = (const float*)d_in[10];
    float* out = (float*)d_out;

    unsigned short* zb   = (unsigned short*)d_ws;               // BHL bf16
    unsigned short* y2   = zb + (size_t)BHL + SPAD;             // 2*BHL bf16
    unsigned short* xbf  = y2 + 2 * (size_t)BHL + SPAD;         // BHL bf16
    unsigned short* mats = xbf + (size_t)BHL + SPAD;            // 512*20480 bf16
    float2* Wc = (float2*)(mats + 512 * (size_t)MATS_PER);      // 512*64 cplx
    unsigned short* Wbf = (unsigned short*)(Wc + 512 * 64);     // 65536 bf16

    mats_kernel<<<512, 64, 0, stream>>>(log_dt, A_re, A_im, C_re, C_im, mats, Wc);
    wbf_kernel<<<64, 256, 0, stream>>>(W, Wbf);
    ln_kernel<<<dim3(L_ / 256, B_), 256, 0, stream>>>(x, lnw, lnb, zb, xbf);
    ssm_kernel<<<B_ * H_ * 2, 128, 0, stream>>>(zb, mats, Wc, D, y2);
    outproj_kernel<<<dim3(L_ / 128, H_ / 128, B_), 256, 0, stream>>>(y2, Wbf, xbf, bout, out);
}

// Round 16
// 188.819 us; speedup vs baseline: 1.0225x; 1.0180x over previous
//
#include <hip/hip_runtime.h>
#include <math.h>

#define B_ 16
#define H_ 256
#define L_ 4096
#define N_ 64
#define HN (H_*N_)
#define HL (H_*L_)
#define BHL (B_*H_*L_)
#define SPAD 64

#define WVT_OFS 0
#define TM_OFS  8192
#define E2T_OFS 12288
#define MATS_PER 20480

typedef short bf16x8 __attribute__((ext_vector_type(8)));
typedef float f32x4  __attribute__((ext_vector_type(4)));

__device__ __forceinline__ unsigned int pk2(float a, float b) {
    return ((__float_as_uint(a) + 0x8000u) >> 16) |
           ((__float_as_uint(b) + 0x8000u) & 0xffff0000u);
}
__device__ __forceinline__ unsigned short bfr(float a) {
    return (unsigned short)((__float_as_uint(a) + 0x8000u) >> 16);
}
__device__ __forceinline__ float ubf(unsigned short u) {
    return __uint_as_float(((unsigned int)u) << 16);
}

// ---------------------------------------------------------------------------
// Kernel 1: build per-(h,dir) matrices + w^64. 1 wave per (h,dir).
// ---------------------------------------------------------------------------
__global__ void __launch_bounds__(64) mats_kernel(const float* __restrict__ log_dt,
                                                  const float* __restrict__ A_re,
                                                  const float* __restrict__ A_im,
                                                  const float* __restrict__ C_re,
                                                  const float* __restrict__ C_im,
                                                  unsigned short* __restrict__ mats,
                                                  float2* __restrict__ Wc) {
    int hd = blockIdx.x;
    int h = hd >> 1, d = hd & 1;
    int m = threadIdx.x;
    __shared__ float2 pws[65 * 64];
    __shared__ float2 c2s[64];
    __shared__ float  Karr[64];

    int i = h * 64 + m;
    float dt = expf(log_dt[h]);
    float Are = A_re[i], Aim = A_im[i];
    float dr = dt * Are, di = dt * Aim;
    float er = expf(dr);
    float wr = er * cosf(di), wi = er * sinf(di);
    float em1r = wr - 1.0f, em1i = wi;
    float inv = 1.0f / (Are * Are + Aim * Aim);
    float qr = (em1r * Are + em1i * Aim) * inv;
    float qi = (em1i * Are - em1r * Aim) * inv;
    float Cr = C_re[d * HN + i], Ci = C_im[d * HN + i];
    float2 c2;
    c2.x = 2.0f * (Cr * qr - Ci * qi);
    c2.y = 2.0f * (Cr * qi + Ci * qr);
    c2s[m] = c2;
    float pr = 1.0f, pi = 0.0f;
    for (int k = 0; k < 64; ++k) {
        float2 p; p.x = pr; p.y = pi;
        pws[k * 64 + ((m + k) & 63)] = p;
        float t = pr * wr - pi * wi;
        pi = pr * wi + pi * wr;
        pr = t;
    }
    {
        float2 p; p.x = pr; p.y = pi;
        pws[64 * 64 + ((m + 64) & 63)] = p;
        Wc[hd * 64 + m] = p;
    }
    __syncthreads();
    {
        float kk = 0.f;
        for (int mm = 0; mm < 64; ++mm) {
            float2 c = c2s[mm];
            float2 pw = pws[m * 64 + ((mm + m) & 63)];
            kk += c.x * pw.x - c.y * pw.y;
        }
        Karr[m] = kk;
    }
    __syncthreads();
    unsigned short* mb = mats + (size_t)hd * MATS_PER;
    for (int i2 = 0; i2 < 32; ++i2) {
        int e0 = 2 * i2, e1 = e0 + 1;
        int k0 = d ? e0 : 63 - e0;
        int k1 = d ? e1 : 63 - e1;
        float2 p0 = pws[k0 * 64 + ((m + k0) & 63)];
        float2 p1 = pws[k1 * 64 + ((m + k1) & 63)];
        *(unsigned int*)(mb + WVT_OFS + (2 * m) * 64 + e0)     = pk2(p0.x, p1.x);
        *(unsigned int*)(mb + WVT_OFS + (2 * m + 1) * 64 + e0) = pk2(p0.y, p1.y);
    }
    for (int i2 = 0; i2 < 32; ++i2) {
        int e0 = 2 * i2, e1 = e0 + 1;
        float v0, v1;
        if (d == 0) {
            v0 = (e0 <= m) ? Karr[m - e0] : 0.f;
            v1 = (e1 <= m) ? Karr[m - e1] : 0.f;
        } else {
            v0 = (e0 > m) ? Karr[e0 - m - 1] : 0.f;
            v1 = (e1 > m) ? Karr[e1 - m - 1] : 0.f;
        }
        *(unsigned int*)(mb + TM_OFS + m * 64 + e0) = pk2(v0, v1);
    }
    {
        int kp = d ? (63 - m) : (m + 1);
        for (int mm = 0; mm < 64; ++mm) {
            float2 c = c2s[mm];
            float2 pw = pws[kp * 64 + ((mm + kp) & 63)];
            float vr = c.x * pw.x - c.y * pw.y;
            float vi = -(c.x * pw.y + c.y * pw.x);
            *(unsigned int*)(mb + E2T_OFS + m * 128 + 2 * mm) = pk2(vr, vi);
        }
    }
}

// ---------------------------------------------------------------------------
// Kernel 1b: W fp32 -> bf16
// ---------------------------------------------------------------------------
__global__ void __launch_bounds__(256) wbf_kernel(const float* __restrict__ W,
                                                  unsigned short* __restrict__ Wbf) {
    int i = (blockIdx.x * 256 + threadIdx.x) * 4;
    float4 v = *(const float4*)(W + i);
    uint2 u;
    u.x = pk2(v.x, v.y);
    u.y = pk2(v.z, v.w);
    *(uint2*)(Wbf + i) = u;
}

// ---------------------------------------------------------------------------
// Kernel 2: LayerNorm over channel dim H; writes z bf16 AND x bf16 copy.
// ---------------------------------------------------------------------------
__global__ void __launch_bounds__(256) ln_kernel(const float* __restrict__ x,
                                                 const float* __restrict__ lnw,
                                                 const float* __restrict__ lnb,
                                                 unsigned short* __restrict__ zb,
                                                 unsigned short* __restrict__ xbf) {
    int b  = blockIdx.y;
    int l0 = blockIdx.x * 256;
    int t  = threadIdx.x;
    int hq = t >> 6, lo = t & 63;
    int l  = l0 + lo * 4;
    __shared__ float4 r1[4][64];
    __shared__ float4 r2[4][64];
    __shared__ float4 muS[64];
    __shared__ float4 rsS[64];
    const float* xb = x + (size_t)b * HL;
    float4 s1 = {0.f,0.f,0.f,0.f}, s2 = {0.f,0.f,0.f,0.f};
    #pragma unroll 4
    for (int hh = 0; hh < 64; ++hh) {
        int h = hq * 64 + hh;
        float4 v = *(const float4*)(xb + (size_t)h * L_ + l);
        s1.x += v.x; s1.y += v.y; s1.z += v.z; s1.w += v.w;
        s2.x += v.x*v.x; s2.y += v.y*v.y; s2.z += v.z*v.z; s2.w += v.w*v.w;
    }
    r1[hq][lo] = s1; r2[hq][lo] = s2;
    __syncthreads();
    if (t < 64) {
        float4 S1 = r1[0][t], S2 = r2[0][t];
        #pragma unroll
        for (int q = 1; q < 4; ++q) {
            float4 a = r1[q][t], c = r2[q][t];
            S1.x += a.x; S1.y += a.y; S1.z += a.z; S1.w += a.w;
            S2.x += c.x; S2.y += c.y; S2.z += c.z; S2.w += c.w;
        }
        const float invH = 1.0f / 256.0f;
        float4 mu, rs;
        mu.x = S1.x*invH; mu.y = S1.y*invH; mu.z = S1.z*invH; mu.w = S1.w*invH;
        rs.x = rsqrtf(S2.x*invH - mu.x*mu.x + 1e-5f);
        rs.y = rsqrtf(S2.y*invH - mu.y*mu.y + 1e-5f);
        rs.z = rsqrtf(S2.z*invH - mu.z*mu.z + 1e-5f);
        rs.w = rsqrtf(S2.w*invH - mu.w*mu.w + 1e-5f);
        muS[t] = mu; rsS[t] = rs;
    }
    __syncthreads();
    float4 mu = muS[lo], rs = rsS[lo];
    #pragma unroll 4
    for (int hh = 0; hh < 64; ++hh) {
        int h = hq * 64 + hh;
        float w = lnw[h], bb = lnb[h];
        float4 v = *(const float4*)(xb + (size_t)h * L_ + l);
        float4 zz;
        zz.x = (v.x - mu.x) * rs.x * w + bb;
        zz.y = (v.y - mu.y) * rs.y * w + bb;
        zz.z = (v.z - mu.z) * rs.z * w + bb;
        zz.w = (v.w - mu.w) * rs.w * w + bb;
        uint2 u;
        u.x = pk2(zz.x, zz.y);
        u.y = pk2(zz.z, zz.w);
        *(uint2*)(zb + (size_t)b * HL + (size_t)h * L_ + l) = u;
        uint2 ux;
        ux.x = pk2(v.x, v.y);
        ux.y = pk2(v.z, v.w);
        *(uint2*)(xbf + (size_t)b * HL + (size_t)h * L_ + l) = ux;
    }
}

// ---------------------------------------------------------------------------
// Kernel 3: per-(b,h,dir) MFMA chunked S4D. Scan software-pipelined in
// 16-element register groups (static-indexed, double-buffered).
// ---------------------------------------------------------------------------
#define MFMA16(a,b,c) __builtin_amdgcn_mfma_f32_16x16x32_bf16((a),(b),(c),0,0,0)
#define SU_BASE 8192

__global__ void __launch_bounds__(128, 3) ssm_kernel(const unsigned short* __restrict__ zb,
                                                     const unsigned short* __restrict__ mats,
                                                     const float2* __restrict__ Wc,
                                                     const float* __restrict__ D,
                                                     unsigned short* __restrict__ y2) {
    int bhd = blockIdx.x;
    int d  = bhd & 1;
    int bh = bhd >> 1;
    int h  = bh & (H_ - 1);
    int t  = threadIdx.x;
    int w  = t >> 6, l = t & 63;
    int p  = w;

    __shared__ __align__(16) char smem[24576];

    const unsigned short* mb = mats + (size_t)(h * 2 + d) * MATS_PER;

    {
        const char* zrow = (const char*)(zb + (size_t)bh * L_);
        #pragma unroll
        for (int k = 0; k < 4; ++k) {
            int row = w * 32 + k * 8 + (l >> 3);
            int chunk = (l & 7) ^ (row & 7);
            const char* src = zrow + row * 128 + chunk * 16;
            __builtin_amdgcn_global_load_lds(
                (const __attribute__((address_space(1))) unsigned int*)src,
                (__attribute__((address_space(3))) unsigned int*)(smem + w * 4096 + k * 1024),
                16, 0, 0);
        }
    }
    __syncthreads();

    bf16x8 za[4][2];
    int arow = l & 15;
    int koff = (l >> 4) * 8;
    #pragma unroll
    for (int cb = 0; cb < 4; ++cb) {
        int row = cb * 16 + arow;
        unsigned int sw = (row & 7) << 4;
        #pragma unroll
        for (int kb = 0; kb < 2; ++kb) {
            unsigned int byte = (unsigned)(row * 128 + (kb * 32 + koff) * 2) ^ sw;
            za[cb][kb] = *(bf16x8*)(smem + byte);
        }
    }

    char* sUd = smem + SU_BASE;
    #pragma unroll
    for (int mcb = 0; mcb < 4; ++mcb) {
        int mcblk = p * 4 + mcb;
        const unsigned short* wv = mb + WVT_OFS + (mcblk * 16 + arow) * 64 + koff;
        bf16x8 b0 = *(const bf16x8*)(wv);
        bf16x8 b1 = *(const bf16x8*)(wv + 32);
        #pragma unroll
        for (int cb = 0; cb < 4; ++cb) {
            f32x4 acc = {0.f, 0.f, 0.f, 0.f};
            acc = MFMA16(za[cb][0], b0, acc);
            acc = MFMA16(za[cb][1], b1, acc);
            int mc = mcblk * 16 + arow;
            #pragma unroll
            for (int rr = 0; rr < 4; ++rr) {
                int c = cb * 16 + (l >> 4) * 4 + rr;
                unsigned int byte = ((unsigned)(c * 256 + mc * 2)) ^ ((c & 7) << 4);
                *(unsigned short*)(sUd + byte) = bfr(acc[rr]);
            }
        }
    }
    __syncthreads();

    // ---- scan (wave 0; lane = mode): pipelined 16-element register groups ----
    if (p == 0) {
        float2 w64 = Wc[(h * 2 + d) * 64 + l];
        float sr = 0.f, si = 0.f;
        unsigned int ua[16], ub[16];
#define SBYTE(c) (((unsigned)((c) * 256 + l * 4)) ^ (((unsigned)(c) & 7u) << 4))
#define SPREF(buf, g)                                                      \
        _Pragma("unroll")                                                  \
        for (int k = 0; k < 16; ++k) {                                     \
            int c = (d == 0) ? ((g) * 16 + k) : (63 - ((g) * 16 + k));     \
            buf[k] = *(unsigned int*)(sUd + SBYTE(c));                     \
        }
#define SPROC(buf, g)                                                      \
        _Pragma("unroll")                                                  \
        for (int k = 0; k < 16; ++k) {                                     \
            int c = (d == 0) ? ((g) * 16 + k) : (63 - ((g) * 16 + k));     \
            unsigned int uu = buf[k];                                      \
            *(unsigned int*)(sUd + SBYTE(c)) = pk2(sr, si);                \
            float ur = __uint_as_float(uu << 16);                          \
            float ui = __uint_as_float(uu & 0xffff0000u);                  \
            float nsr = fmaf(w64.x, sr, fmaf(-w64.y, si, ur));             \
            float nsi = fmaf(w64.x, si, fmaf(w64.y, sr, ui));              \
            sr = nsr; si = nsi;                                            \
        }
        SPREF(ua, 0)
        SPREF(ub, 1)
        SPROC(ua, 0)
        SPREF(ua, 2)
        SPROC(ub, 1)
        SPREF(ub, 3)
        SPROC(ua, 2)
        SPROC(ub, 3)
#undef SBYTE
#undef SPREF
#undef SPROC
    }
    __syncthreads();

    f32x4 yacc[2][4];
    #pragma unroll
    for (int jb = 0; jb < 2; ++jb) {
        int jblk = p * 2 + jb;
        const unsigned short* tm = mb + TM_OFS + (jblk * 16 + arow) * 64 + koff;
        bf16x8 tb0 = *(const bf16x8*)(tm);
        bf16x8 tb1 = *(const bf16x8*)(tm + 32);
        const unsigned short* et = mb + E2T_OFS + (jblk * 16 + arow) * 128 + koff;
        bf16x8 eb0 = *(const bf16x8*)(et);
        bf16x8 eb1 = *(const bf16x8*)(et + 32);
        bf16x8 eb2 = *(const bf16x8*)(et + 64);
        bf16x8 eb3 = *(const bf16x8*)(et + 96);
        #pragma unroll
        for (int cb = 0; cb < 4; ++cb) {
            f32x4 acc = {0.f, 0.f, 0.f, 0.f};
            acc = MFMA16(za[cb][0], tb0, acc);
            acc = MFMA16(za[cb][1], tb1, acc);
            int row = cb * 16 + arow;
            unsigned int sw = (row & 7) << 4;
            bf16x8 sa0 = *(bf16x8*)(sUd + (((unsigned)(row * 256 + (0 * 32 + koff) * 2)) ^ sw));
            bf16x8 sa1 = *(bf16x8*)(sUd + (((unsigned)(row * 256 + (1 * 32 + koff) * 2)) ^ sw));
            bf16x8 sa2 = *(bf16x8*)(sUd + (((unsigned)(row * 256 + (2 * 32 + koff) * 2)) ^ sw));
            bf16x8 sa3 = *(bf16x8*)(sUd + (((unsigned)(row * 256 + (3 * 32 + koff) * 2)) ^ sw));
            acc = MFMA16(sa0, eb0, acc);
            acc = MFMA16(sa1, eb1, acc);
            acc = MFMA16(sa2, eb2, acc);
            acc = MFMA16(sa3, eb3, acc);
            yacc[jb][cb] = acc;
        }
    }
    __syncthreads();

    {
        float dv = D[h];
        #pragma unroll
        for (int jb = 0; jb < 2; ++jb) {
            int j = (p * 2 + jb) * 16 + arow;
            #pragma unroll
            for (int cb = 0; cb < 4; ++cb) {
                #pragma unroll
                for (int rr = 0; rr < 4; ++rr) {
                    int c = cb * 16 + (l >> 4) * 4 + rr;
                    unsigned int byte = ((unsigned)(c * 128 + j * 2)) ^ ((c & 7) << 4);
                    float val = yacc[jb][cb][rr];
                    if (d == 0) val += dv * ubf(*(unsigned short*)(smem + byte));
                    *(unsigned short*)(smem + byte) = bfr(val);
                }
            }
        }
    }
    __syncthreads();
    {
        int row = t >> 1, halfq = t & 1;
        unsigned int rsw = (row & 7) << 4;
        char* go = (char*)(y2 + ((size_t)bh * 2 + d) * L_);
        #pragma unroll
        for (int j = 0; j < 4; ++j) {
            unsigned int off = (unsigned)(row * 128 + halfq * 64 + j * 16);
            uint4 a = *(const uint4*)(smem + (off ^ rsw));
            *(uint4*)(go + off) = a;
        }
    }
}

// ---------------------------------------------------------------------------
// Kernel 4: out[b,o,l] = xbf + b_out[o] + sum_h W[o,h]*gelu(yf+yb).
// ---------------------------------------------------------------------------
__global__ void __launch_bounds__(256, 3) outproj_kernel(
        const unsigned short* __restrict__ y2,
        const unsigned short* __restrict__ Wbf,
        const unsigned short* __restrict__ xbf,
        const float* __restrict__ bias,
        float* __restrict__ out) {
    int b  = blockIdx.z;
    int o0 = blockIdx.y * 128;
    int l0 = blockIdx.x * 128;
    int t  = threadIdx.x;
    int w  = t >> 6, lane = t & 63;
    int wr = w >> 1, wc = w & 1;
    int l15 = lane & 15, q = lane >> 4;

    __shared__ __align__(16) char lds[34816];
    unsigned short* At = (unsigned short*)lds;
    unsigned short* Bt = (unsigned short*)(lds + 16384);

    f32x4 acc[4][4];
    #pragma unroll
    for (int i = 0; i < 4; ++i)
        #pragma unroll
        for (int j = 0; j < 4; ++j) acc[i][j] = (f32x4){0.f, 0.f, 0.f, 0.f};

    const unsigned short* Wb0 = Wbf + (size_t)o0 * 256;
    unsigned int swz = (unsigned)(l15 & 7) << 4;

    int h_loc = t >> 2, lq = t & 3;

    for (int kt = 0; kt < 4; ++kt) {
        int k0 = kt * 64;
        {
            const unsigned short* yb0 =
                y2 + (((size_t)b * H_ + k0 + h_loc) * 2) * L_ + l0 + lq * 32;
            uint4 f[4], g[4];
            #pragma unroll
            for (int j = 0; j < 4; ++j) f[j] = *(const uint4*)(yb0 + j * 8);
            #pragma unroll
            for (int j = 0; j < 4; ++j) g[j] = *(const uint4*)(yb0 + L_ + j * 8);
            #pragma unroll
            for (int j = 0; j < 4; ++j) {
                #pragma unroll
                for (int e = 0; e < 8; ++e) {
                    int l_loc = lq * 32 + j * 8 + e;
                    float y = ubf(((const unsigned short*)&f[j])[e]) +
                              ubf(((const unsigned short*)&g[j])[e]);
                    float inner = 0.7978845608028654f * (y + 0.044715f * y * y * y);
                    float en = __expf(-2.0f * inner);
                    float gv = y * __builtin_amdgcn_rcpf(1.0f + en);
                    *(unsigned short*)((char*)At +
                        (((unsigned)(l_loc * 128 + h_loc * 2)) ^ ((l_loc & 7) << 4))) = bfr(gv);
                }
            }
        }
        #pragma unroll
        for (int s = 0; s < 4; ++s) {
            int id = (w * 4 + s) * 64 + lane;
            int row = id >> 3, ch = id & 7;
            int chl = ch ^ (row & 7);
            uint4 vb = *(const uint4*)(Wb0 + (size_t)row * 256 + k0 + chl * 8);
            *(uint4*)(Bt + id * 8) = vb;
        }
        __syncthreads();
        #pragma unroll
        for (int kk = 0; kk < 2; ++kk) {
            bf16x8 af[4], bfr_[4];
            #pragma unroll
            for (int rb = 0; rb < 4; ++rb) {
                int li = wr * 64 + rb * 16 + l15;
                af[rb] = *(const bf16x8*)((char*)At + li * 128 + (((kk * 64 + q * 16)) ^ swz));
                int oi = wc * 64 + rb * 16 + l15;
                bfr_[rb] = *(const bf16x8*)((char*)Bt + oi * 128 + (((kk * 64 + q * 16)) ^ swz));
            }
            #pragma unroll
            for (int rb = 0; rb < 4; ++rb)
                #pragma unroll
                for (int cb = 0; cb < 4; ++cb)
                    acc[rb][cb] = MFMA16(af[rb], bfr_[cb], acc[rb][cb]);
        }
        __syncthreads();
    }

    float* Eb = (float*)lds;
    for (int pp = 0; pp < 2; ++pp) {
        if (wc == pp) {
            #pragma unroll
            for (int cb = 0; cb < 4; ++cb) {
                int o_loc = cb * 16 + l15;
                unsigned int esw = (unsigned)(o_loc & 7) << 4;
                #pragma unroll
                for (int rb = 0; rb < 4; ++rb) {
                    int colbase = wr * 64 + rb * 16 + q * 4;
                    #pragma unroll
                    for (int r = 0; r < 4; ++r) {
                        int col = colbase + r;
                        *(float*)((char*)Eb + o_loc * 528 + (((unsigned)(col * 4)) ^ esw)) =
                            acc[rb][cb][r];
                    }
                }
            }
        }
        __syncthreads();
        int o_loc = t >> 2, lseg = t & 3;
        int o = o0 + pp * 64 + o_loc;
        float bo = bias[o];
        unsigned int esw = (unsigned)(o_loc & 7) << 4;
        size_t off = ((size_t)b * H_ + o) * L_ + l0 + lseg * 32;
        const unsigned short* xr = xbf + off;
        float* orow = out + off;
        #pragma unroll
        for (int j = 0; j < 8; ++j) {
            float4 e = *(const float4*)((char*)Eb + o_loc * 528 +
                                        (((unsigned)(lseg * 128 + j * 16)) ^ esw));
            uint2 xv2 = *(const uint2*)(xr + j * 4);
            float4 ov;
            ov.x = ubf((unsigned short)(xv2.x & 0xffffu))  + bo + e.x;
            ov.y = ubf((unsigned short)(xv2.x >> 16))      + bo + e.y;
            ov.z = ubf((unsigned short)(xv2.y & 0xffffu))  + bo + e.z;
            ov.w = ubf((unsigned short)(xv2.y >> 16))      + bo + e.w;
            *(float4*)(orow + j * 4) = ov;
        }
        __syncthreads();
    }
}

// ---------------------------------------------------------------------------
extern "C" void kernel_launch(void* const* d_in, const int* in_sizes, int n_in,
                              void* d_out, int out_size, void* d_ws, size_t ws_size,
                              hipStream_t stream) {
    const float* x      = (const float*)d_in[0];
    const float* log_dt = (const float*)d_in[1];
    const float* A_re   = (const float*)d_in[2];
    const float* A_im   = (const float*)d_in[3];
    const float* C_re   = (const float*)d_in[4];
    const float* C_im   = (const float*)d_in[5];
    const float* D      = (const float*)d_in[6];
    const float* lnw    = (const float*)d_in[7];
    const float* lnb    = (const float*)d_in[8];
    const float* W      = (const float*)d_in[9];
    const float* bout   = (const float*)d_in[10];
    float* out = (float*)d_out;

    unsigned short* zb   = (unsigned short*)d_ws;               // BHL bf16
    unsigned short* y2   = zb + (size_t)BHL + SPAD;             // 2*BHL bf16
    unsigned short* xbf  = y2 + 2 * (size_t)BHL + SPAD;         // BHL bf16
    unsigned short* mats = xbf + (size_t)BHL + SPAD;            // 512*20480 bf16
    float2* Wc = (float2*)(mats + 512 * (size_t)MATS_PER);      // 512*64 cplx
    unsigned short* Wbf = (unsigned short*)(Wc + 512 * 64);     // 65536 bf16

    mats_kernel<<<512, 64, 0, stream>>>(log_dt, A_re, A_im, C_re, C_im, mats, Wc);
    wbf_kernel<<<64, 256, 0, stream>>>(W, Wbf);
    ln_kernel<<<dim3(L_ / 256, B_), 256, 0, stream>>>(x, lnw, lnb, zb, xbf);
    ssm_kernel<<<B_ * H_ * 2, 128, 0, stream>>>(zb, mats, Wc, D, y2);
    outproj_kernel<<<dim3(L_ / 128, H_ / 128, B_), 256, 0, stream>>>(y2, Wbf, xbf, bout, out);
}